// Round 16
// baseline (322.686 us; speedup 1.0000x reference)
//
#include <hip/hip_runtime.h>
#include <hip/hip_bf16.h>
#include <math.h>

#define NPOS 8192   // B*H*W = 8*32*32
#define DIMC 384
#define DIN 768
#define DST 16
#define CHUNK 16
#define NCH 64      // 1024 / CHUNK

typedef unsigned int uint;
typedef __attribute__((ext_vector_type(8))) short bf16x8;
typedef __attribute__((ext_vector_type(4))) float f32x4;

__device__ __forceinline__ float b2f(unsigned short u) {
    return __uint_as_float(((unsigned int)u) << 16);
}
__device__ __forceinline__ uint cvt_pk(float lo, float hi) {
    uint r;
    asm("v_cvt_pk_bf16_f32 %0, %1, %2" : "=v"(r) : "v"(lo), "v"(hi));
    return r;
}
__device__ __forceinline__ unsigned short f2b1(float f) {
    return (unsigned short)cvt_pk(f, f);
}
__device__ __forceinline__ float frcp(float x) {
    float r;
    asm("v_rcp_f32 %0, %1" : "=v"(r) : "v"(x));
    return r;
}
__device__ __forceinline__ float fexp2(float x) {   // 2^x, 1 instr
    float r;
    asm("v_exp_f32 %0, %1" : "=v"(r) : "v"(x));
    return r;
}
__device__ __forceinline__ void ub8(uint4 u, float* o) {
    o[0] = b2f((unsigned short)(u.x & 0xffff));
    o[1] = b2f((unsigned short)(u.x >> 16));
    o[2] = b2f((unsigned short)(u.y & 0xffff));
    o[3] = b2f((unsigned short)(u.y >> 16));
    o[4] = b2f((unsigned short)(u.z & 0xffff));
    o[5] = b2f((unsigned short)(u.z >> 16));
    o[6] = b2f((unsigned short)(u.w & 0xffff));
    o[7] = b2f((unsigned short)(u.w >> 16));
}
__device__ __forceinline__ void ld_bf8(const unsigned short* p, float* o) {
    ub8(*(const uint4*)p, o);
}
__device__ __forceinline__ uint4 pack_bf8(const float* o) {
    uint4 p;
    p.x = cvt_pk(o[0], o[1]);
    p.y = cvt_pk(o[2], o[3]);
    p.z = cvt_pk(o[4], o[5]);
    p.w = cvt_pk(o[6], o[7]);
    return p;
}
#define LOG2E 1.442695040888963f

// ---------------------------------------------------------------- LayerNorm -> bf16 xn
__global__ __launch_bounds__(256) void k_ln(const float* __restrict__ x,
        const float* __restrict__ g, const float* __restrict__ bta,
        unsigned short* __restrict__ xnb, float* __restrict__ xg) {
    int wid = blockIdx.x * 4 + (threadIdx.x >> 6);
    int lane = threadIdx.x & 63;
    const float* xr = x + (size_t)wid * DIMC;
    float v[6];
    float s = 0.f, ss = 0.f;
#pragma unroll
    for (int i = 0; i < 6; i++) {
        v[i] = xr[lane + i * 64];
        s += v[i]; ss += v[i] * v[i];
    }
#pragma unroll
    for (int m = 32; m; m >>= 1) { s += __shfl_xor(s, m); ss += __shfl_xor(ss, m); }
    float mu = s * (1.f / DIMC);
    float var = ss * (1.f / DIMC) - mu * mu;
    float rstd = rsqrtf(var + 1e-5f);
    unsigned short* xnr = xnb + (size_t)wid * DIMC;
    float sn = 0.f;
#pragma unroll
    for (int i = 0; i < 6; i++) {
        int c = lane + i * 64;
        float o = (v[i] - mu) * rstd * g[c] + bta[c];
        xnr[c] = f2b1(o);
        sn += o;
    }
#pragma unroll
    for (int m = 32; m; m >>= 1) sn += __shfl_xor(sn, m);
    if (lane == 0) xg[wid] = sn * (1.f / DIMC);
}

// ---------------------------------------------------------------- direction
__global__ __launch_bounds__(256) void k_dir(const float* __restrict__ xg,
        const float* __restrict__ w1, const float* __restrict__ b1,
        const float* __restrict__ w2, const float* __restrict__ b2,
        int* __restrict__ vert) {
    __shared__ float sg[32][32];
    __shared__ float red[4][4];
    int b = blockIdx.x;
    int tid = threadIdx.x;
    for (int i = tid; i < 1024; i += 256) sg[i >> 5][i & 31] = xg[b * 1024 + i];
    __syncthreads();
    float ph = 0, pv = 0, pd = 0, pa = 0;
    const float iks = 1.f / 1.0625f;   // kernel_scale = 34/32 (antialias)
    for (int p = tid; p < 1024; p += 256) {
        int y = p >> 5, xq = p & 31;
        int xl = (xq >= 1) ? xq - 1 : 1;
        int xr2 = (xq <= 30) ? xq + 1 : 30;
        float sf = (y + 0.5f) * 1.0625f - 0.5f;
        int jlo = (int)ceilf(sf - 1.0625f); if (jlo < 0) jlo = 0;
        int jhi = (int)floorf(sf + 1.0625f); if (jhi > 33) jhi = 33;
        float acc = 0.f, wsum = 0.f;
        for (int j = jlo; j <= jhi; j++) {
            float wgt = 1.f - fabsf(sf - j) * iks;
            if (wgt <= 0.f) continue;
            int ry = (j >= 1) ? ((j <= 32) ? j - 1 : 30) : 1;
            acc += wgt * fabsf(sg[ry][xr2] - sg[ry][xl]);
            wsum += wgt;
        }
        float ghr = acc / wsum;
        int yu = (y >= 1) ? y - 1 : 1;
        int yd = (y <= 30) ? y + 1 : 30;
        float sfx = (xq + 0.5f) * 1.0625f - 0.5f;
        int ilo = (int)ceilf(sfx - 1.0625f); if (ilo < 0) ilo = 0;
        int ihi = (int)floorf(sfx + 1.0625f); if (ihi > 33) ihi = 33;
        float accv = 0.f, wsv = 0.f;
        for (int i = ilo; i <= ihi; i++) {
            float wgt = 1.f - fabsf(sfx - i) * iks;
            if (wgt <= 0.f) continue;
            int rx = (i >= 1) ? ((i <= 32) ? i - 1 : 30) : 1;
            accv += wgt * fabsf(sg[yd][rx] - sg[yu][rx]);
            wsv += wgt;
        }
        float gvr = accv / wsv;
        float gd = (ghr + gvr) * 0.5f;
        float ga = fabsf(ghr - gvr);
        float cw = ((y == 0 || y == 31) ? 2.f : 3.f) * ((xq == 0 || xq == 31) ? 2.f : 3.f);
        ph += ghr * cw; pv += gvr * cw; pd += gd * cw; pa += ga * cw;
    }
#pragma unroll
    for (int m = 32; m; m >>= 1) {
        ph += __shfl_xor(ph, m); pv += __shfl_xor(pv, m);
        pd += __shfl_xor(pd, m); pa += __shfl_xor(pa, m);
    }
    int wv = tid >> 6;
    if ((tid & 63) == 0) { red[wv][0] = ph; red[wv][1] = pv; red[wv][2] = pd; red[wv][3] = pa; }
    __syncthreads();
    if (tid == 0) {
        float sc[4];
        for (int k = 0; k < 4; k++)
            sc[k] = (red[0][k] + red[1][k] + red[2][k] + red[3][k]) * (1.f / 9216.f);
        float hdn[32];
        for (int j = 0; j < 32; j++) {
            float a = b1[j];
            for (int i = 0; i < 4; i++) a += sc[i] * w1[i * 32 + j];
            hdn[j] = a > 0.f ? a : 0.f;
        }
        float best = -1e30f; int bi = 0;
        for (int k = 0; k < 4; k++) {
            float a = b2[k];
            for (int j = 0; j < 32; j++) a += hdn[j] * w2[j * 4 + k];
            if (a > best) { best = a; bi = k; }
        }
        vert[b] = (bi == 1) ? 1 : 0;
    }
}

// ---------------------------------------------------------------- unified weight prep
// blocks [0,576): inw->inwT; [576,1152): dtw->dtwTp; [1152,1176): xpw->dtwTp+768*768;
// [1176,1464): outw->outwT; [1464,1536): zero pad rows 800..895 of dtwTp
__device__ __forceinline__ void wt_body(const float* __restrict__ W,
        unsigned short* __restrict__ WT, int K, int N, int bid, int tid,
        float (*t)[33]) {
    int nb = N >> 5;
    int n0 = (bid % nb) << 5, k0 = (bid / nb) << 5;
    int kr = tid >> 3, n4 = (tid & 7) << 2;
    float4 v = *(const float4*)(W + (size_t)(k0 + kr) * N + n0 + n4);
    t[kr][n4 + 0] = v.x; t[kr][n4 + 1] = v.y; t[kr][n4 + 2] = v.z; t[kr][n4 + 3] = v.w;
    __syncthreads();
    int nr = tid >> 3, k4 = (tid & 7) << 2;
    ushort4 o;
    o.x = f2b1(t[k4 + 0][nr]); o.y = f2b1(t[k4 + 1][nr]);
    o.z = f2b1(t[k4 + 2][nr]); o.w = f2b1(t[k4 + 3][nr]);
    *(ushort4*)(WT + (size_t)(n0 + nr) * K + k0 + k4) = o;
}

__global__ __launch_bounds__(256) void k_prep(const float* __restrict__ inw,
        const float* __restrict__ dtw, const float* __restrict__ xpw,
        const float* __restrict__ outw,
        unsigned short* __restrict__ inwT, unsigned short* __restrict__ dtwTp,
        unsigned short* __restrict__ outwT) {
    __shared__ float t[32][33];
    int bid = blockIdx.x;
    int tid = threadIdx.x;
    if (bid < 576) {
        wt_body(inw, inwT, 384, 1536, bid, tid, t);
    } else if (bid < 1152) {
        wt_body(dtw, dtwTp, 768, 768, bid - 576, tid, t);
    } else if (bid < 1176) {
        wt_body(xpw, dtwTp + 768 * 768, 768, 32, bid - 1152, tid, t);
    } else if (bid < 1464) {
        wt_body(outw, outwT, 768, 384, bid - 1176, tid, t);
    } else {
        int i = (bid - 1464) * 256 + tid;
        if (i < (96 * 768) / 4)
            *(ushort4*)(dtwTp + 800 * 768 + i * 4) = (ushort4){0, 0, 0, 0};
    }
}

// ---------------------------------------------------------------- MFMA GEMM
// 128x128 tile, 4 waves, reg-staged dbuf LDS [r][40], 2-deep register prefetch,
// XCD swizzle, LDS-transpose epilogue.
// MODE 0 (in_proj): op1=inwT[1536][384], op2=xn[8192][384]+vert -> xz_T bf16
// MODE 1 (dt+xproj): op1=dtwTp[896][768], op2=xc_rm[8192][768];
//        n0<768: +bias+softplus -> delta_T; n0==768: BCT f32 [8192][32]
// MODE 2 (out): op1=y_rm[8192][768], op2=outwT[384][768] -> f32 row-major + resid
template <int MODE>
__global__ __launch_bounds__(256) void k_mfma(
        const unsigned short* __restrict__ op1,
        const unsigned short* __restrict__ op2,
        void* __restrict__ outp,
        const float* __restrict__ bias,
        const float* __restrict__ resid,
        const int* __restrict__ vert) {
    constexpr int K = (MODE == 0) ? 384 : 768;
    constexpr int NK = K / 32;
    constexpr int NBN = (MODE == 0) ? 12 : (MODE == 1 ? 7 : 3);
    __shared__ unsigned short lds[2][2][128 * 40];   // 40 KB; reused as [128][132] epilogue
    int tid = threadIdx.x;
    int bid = blockIdx.x;
    int xcd = bid & 7;
    int ii = bid >> 3;
    int n0 = (ii % NBN) << 7;
    int m0 = ((xcd << 3) + ii / NBN) << 7;
    int drow = tid >> 1, dkh = (tid & 1) << 4;

    size_t g1row, g2row;
    if constexpr (MODE == 0) {
        g1row = (size_t)(n0 + drow) * 384;
        int m = m0 + drow;
        int b = m >> 10, l = m & 1023;
        int src = vert[b] ? (((l & 31) << 5) | (l >> 5)) : l;
        g2row = ((size_t)(b << 10) + src) * 384;
    } else if constexpr (MODE == 1) {
        g1row = (size_t)(n0 + drow) * 768;
        g2row = (size_t)(m0 + drow) * 768;
    } else {
        g1row = (size_t)(m0 + drow) * 768;
        g2row = (size_t)(n0 + drow) * 768;
    }
    const unsigned short* op1g = op1 + g1row + dkh;
    const unsigned short* op2g = op2 + g2row + dkh;

    f32x4 acc[4][4];
    f32x4 zero = {0.f, 0.f, 0.f, 0.f};
#pragma unroll
    for (int i = 0; i < 4; i++)
#pragma unroll
        for (int j = 0; j < 4; j++) acc[i][j] = zero;

    uint4 sA[4], sB[4];
#define LOADR(dst, k0_)                                   \
    { dst[0] = *(const uint4*)(op1g + (k0_));             \
      dst[1] = *(const uint4*)(op1g + (k0_) + 8);         \
      dst[2] = *(const uint4*)(op2g + (k0_));             \
      dst[3] = *(const uint4*)(op2g + (k0_) + 8); }
#define WRITER(buf_, src)                                 \
    { *(uint4*)&lds[buf_][0][drow * 40 + dkh] = src[0];   \
      *(uint4*)&lds[buf_][0][drow * 40 + dkh + 8] = src[1]; \
      *(uint4*)&lds[buf_][1][drow * 40 + dkh] = src[2];   \
      *(uint4*)&lds[buf_][1][drow * 40 + dkh + 8] = src[3]; }

    int wid = tid >> 6, lane = tid & 63;
    int lr = lane & 15, lg = lane >> 4;
    int o1b = (wid >> 1) << 6;   // op1-row 64-block within tile
    int o2b = (wid & 1) << 6;    // op2-row 64-block within tile

    LOADR(sA, 0)
    WRITER(0, sA)
    LOADR(sA, 32)        // step 1 data
    LOADR(sB, 64)        // step 2 data
    int cur = 0;
    for (int ks = 0; ks < NK; ks++) {
        __syncthreads();   // lds[cur] holds step ks
        const unsigned short* L1 = &lds[cur][0][0];
        const unsigned short* L2 = &lds[cur][1][0];
        bf16x8 f1[4], f2[4];
#pragma unroll
        for (int f = 0; f < 4; f++) f1[f] = *(const bf16x8*)&L1[(o1b + f * 16 + lr) * 40 + (lg << 3)];
#pragma unroll
        for (int f = 0; f < 4; f++) f2[f] = *(const bf16x8*)&L2[(o2b + f * 16 + lr) * 40 + (lg << 3)];
#pragma unroll
        for (int i = 0; i < 4; i++)
#pragma unroll
            for (int j = 0; j < 4; j++)
                acc[i][j] = __builtin_amdgcn_mfma_f32_16x16x32_bf16(f1[i], f2[j], acc[i][j], 0, 0, 0);
        if (ks + 1 < NK) {
            WRITER(cur ^ 1, sA)            // step ks+1 -> other buffer
#pragma unroll
            for (int q = 0; q < 4; q++) sA[q] = sB[q];
            if (ks + 3 < NK) LOADR(sB, (ks + 3) * 32)
        }
        cur ^= 1;
    }

    if constexpr (MODE <= 1) {
        if (MODE == 1 && n0 == 768) {
            if ((wid >> 1) == 0) {   // o1b == 0: rows 0..63 (only 0..31 matter)
                float* BCT_ = (float*)resid;
#pragma unroll
                for (int i = 0; i < 2; i++) {
                    int col = i * 16 + lg * 4;
#pragma unroll
                    for (int j = 0; j < 4; j++) {
                        int mb_ = m0 + o2b + j * 16 + lr;
                        float4 v4;
                        v4.x = acc[i][j][0]; v4.y = acc[i][j][1];
                        v4.z = acc[i][j][2]; v4.w = acc[i][j][3];
                        *(float4*)(BCT_ + (size_t)mb_ * 32 + col) = v4;
                    }
                }
            }
        } else {
            // LDS-transpose epilogue: acc -> lt[128][132] -> coalesced rows
            __syncthreads();
            unsigned short* lt = &lds[0][0][0];
#pragma unroll
            for (int i = 0; i < 4; i++) {
                int nr = o1b + i * 16 + lg * 4;
#pragma unroll
                for (int j = 0; j < 4; j++) {
                    int mc = o2b + j * 16 + lr;
#pragma unroll
                    for (int r = 0; r < 4; r++) {
                        float v = acc[i][j][r];
                        if constexpr (MODE == 1) {
                            v += bias[n0 + nr + r];
                            v = fmaxf(v, 0.f) + __logf(1.f + __expf(-fabsf(v)));   // softplus
                        }
                        lt[(nr + r) * 132 + mc] = f2b1(v);
                    }
                }
            }
            __syncthreads();
            unsigned short* CT = (unsigned short*)outp;
#pragma unroll
            for (int ps = 0; ps < 8; ps++) {
                int row = ps * 16 + (tid >> 4);
                uint4 v = *(const uint4*)&lt[row * 132 + (tid & 15) * 8];
                *(uint4*)(CT + (size_t)(n0 + row) * 8192 + m0 + (tid & 15) * 8) = v;
            }
        }
    } else {
        float* C = (float*)outp;
#pragma unroll
        for (int i = 0; i < 4; i++) {
            int mb_ = m0 + o1b + i * 16 + lg * 4;
#pragma unroll
            for (int j = 0; j < 4; j++) {
                int n = n0 + o2b + j * 16 + lr;
#pragma unroll
                for (int r = 0; r < 4; r++) {
                    int m = mb_ + r;
                    C[(size_t)m * 384 + n] = acc[i][j][r] + resid[(size_t)m * 384 + n];
                }
            }
        }
    }
#undef LOADR
#undef WRITER
}

// ---------------------------------------------------------------- depthwise conv3 + silu
__global__ __launch_bounds__(256) void k_conv(const unsigned short* __restrict__ xzb,
        const float* __restrict__ cw, const float* __restrict__ cb,
        unsigned short* __restrict__ xcT, unsigned short* __restrict__ xcR) {
    __shared__ unsigned short ly[128][64];
    int blk = blockIdx.x;            // 12 dg * 64 mg
    int dg = blk % 12, mg = blk / 12;
    int r0 = mg * 128;
    int tid = threadIdx.x;
    int dl = tid >> 2, tq = tid & 3;
    int d = dg * 64 + dl;
    int t0 = r0 + tq * 32;
    const unsigned short* xr = xzb + (size_t)d * 8192;
    float xx[32];
#pragma unroll
    for (int q = 0; q < 4; q++) ub8(*(const uint4*)(xr + t0 + q * 8), xx + q * 8);
    int l0 = t0 & 1023;
    float xprev = (l0 != 0)   ? b2f(xr[t0 - 1])  : 0.f;
    float xnext = (l0 != 992) ? b2f(xr[t0 + 32]) : 0.f;
    float w0 = cw[d * 3], w1 = cw[d * 3 + 1], w2 = cw[d * 3 + 2], bb = cb[d];
    float o[32];
#pragma unroll
    for (int j = 0; j < 32; j++) {
        float v = bb + w1 * xx[j];
        v += w0 * ((j == 0) ? xprev : xx[j - 1]);
        v += w2 * ((j == 31) ? xnext : xx[j + 1]);
        o[j] = v * frcp(1.f + __expf(-v));
    }
    unsigned short* dstT = xcT + (size_t)d * 8192 + t0;
#pragma unroll
    for (int q = 0; q < 4; q++) *(uint4*)(dstT + q * 8) = pack_bf8(o + q * 8);
#pragma unroll
    for (int j = 0; j < 32; j++) ly[tq * 32 + j][dl] = f2b1(o[j]);
    __syncthreads();
#pragma unroll
    for (int k = 0; k < 4; k++) {
        int i = tid + k * 256;
        int row = i >> 3, sg = i & 7;
        uint4 v = *(const uint4*)&ly[row][sg * 8];
        *(uint4*)(xcR + (size_t)(r0 + row) * 768 + dg * 64 + sg * 8) = v;
    }
}

// ---------------------------------------------------------------- chunked scan (CHUNK=16)
__global__ __launch_bounds__(256) void k_scan1(const unsigned short* __restrict__ xzb,
        const unsigned short* __restrict__ xcT, const float* __restrict__ BCT,
        const float* __restrict__ A_log,
        unsigned short* __restrict__ G, float* __restrict__ sumd) {
    int tid = threadIdx.x;
    int lane = tid & 63;
    int blk = blockIdx.x;              // 8b * 16cg * 12dg
    int dg = blk % 12;
    int cg = (blk / 12) % 16;
    int b  = blk / 192;
    int c = cg * 4 + (tid >> 6);
    int d = dg * 64 + lane;
    int r0i = __builtin_amdgcn_readfirstlane(b * 1024 + c * CHUNK);
    const float* Bu = BCT + (size_t)r0i * 32;   // wave-uniform
    float Avl[16];
#pragma unroll
    for (int q = 0; q < 4; q++) {
        float4 a4 = *(const float4*)(A_log + d * 16 + q * 4);
        Avl[q * 4 + 0] = -__expf(a4.x) * LOG2E;
        Avl[q * 4 + 1] = -__expf(a4.y) * LOG2E;
        Avl[q * 4 + 2] = -__expf(a4.z) * LOG2E;
        Avl[q * 4 + 3] = -__expf(a4.w) * LOG2E;
    }
    const unsigned short* dptr = xzb + (size_t)d * 8192 + r0i;
    const unsigned short* xptr = xcT + (size_t)d * 8192 + r0i;
    uint4 du[2], xu[2];
#pragma unroll
    for (int q = 0; q < 2; q++) {
        du[q] = *(const uint4*)(dptr + q * 8);
        xu[q] = *(const uint4*)(xptr + q * 8);
    }
    float h[16] = {};
    float sd = 0.f;
#pragma unroll
    for (int q = 0; q < 2; q++) {
        float dv[8], xv[8];
        ub8(du[q], dv);
        ub8(xu[q], xv);
#pragma unroll
        for (int j = 0; j < 8; j++) {
            int t = q * 8 + j;
            float dx = dv[j] * xv[j];
            sd += dv[j];
            float Bt[16];
            *(float4*)&Bt[0]  = *(const float4*)(Bu + t * 32);
            *(float4*)&Bt[4]  = *(const float4*)(Bu + t * 32 + 4);
            *(float4*)&Bt[8]  = *(const float4*)(Bu + t * 32 + 8);
            *(float4*)&Bt[12] = *(const float4*)(Bu + t * 32 + 12);
#pragma unroll
            for (int n = 0; n < 16; n++)
                h[n] = fmaf(fexp2(dv[j] * Avl[n]), h[n], dx * Bt[n]);
        }
    }
    unsigned short* gp = G + (((size_t)(b * NCH + c)) * 768 + d) * 16;
    *(uint4*)gp       = pack_bf8(h);
    *(uint4*)(gp + 8) = pack_bf8(h + 8);
    sumd[(size_t)(b * NCH + c) * 768 + d] = sd;
}

__global__ __launch_bounds__(256) void k_scan2(unsigned short* __restrict__ G,
        const float* __restrict__ sumd, const float* __restrict__ A_log) {
    int blk = blockIdx.x;              // 8b * 48dg
    int dg = blk % 48, b = blk / 48;
    int tid = threadIdx.x;
    int dl = tid >> 4, n = tid & 15;
    int d = dg * 16 + dl;
    float Av = -__expf(A_log[d * 16 + n]);
    float H = 0.f;
#pragma unroll 8
    for (int c = 0; c < NCH; c++) {
        size_t gi = (((size_t)(b * NCH + c)) * 768 + d) * 16 + n;
        float Gv = b2f(G[gi]);
        float P = __expf(Av * sumd[(size_t)(b * NCH + c) * 768 + d]);
        G[gi] = f2b1(H);               // carry-in for chunk c
        H = fmaf(P, H, Gv);
    }
}

__global__ __launch_bounds__(256) void k_scan3(const unsigned short* __restrict__ xzb,
        const unsigned short* __restrict__ xcT, const float* __restrict__ BCT,
        const float* __restrict__ A_log, const float* __restrict__ Dp,
        const unsigned short* __restrict__ G, unsigned short* __restrict__ yR) {
    __shared__ unsigned short ly[64][64];   // 8 KB  [t-local][d-local]
    int tid = threadIdx.x;
    int lane = tid & 63;
    int wv = tid >> 6;
    int blk = blockIdx.x;              // 8b * 16cg * 12dg
    int dg = blk % 12;
    int cg = (blk / 12) % 16;
    int b  = blk / 192;
    int c = cg * 4 + wv;
    int d = dg * 64 + lane;
    int r0i = __builtin_amdgcn_readfirstlane(b * 1024 + c * CHUNK);
    const float* Bu = BCT + (size_t)r0i * 32;   // wave-uniform
    float Avl[16];
#pragma unroll
    for (int q = 0; q < 4; q++) {
        float4 a4 = *(const float4*)(A_log + d * 16 + q * 4);
        Avl[q * 4 + 0] = -__expf(a4.x) * LOG2E;
        Avl[q * 4 + 1] = -__expf(a4.y) * LOG2E;
        Avl[q * 4 + 2] = -__expf(a4.z) * LOG2E;
        Avl[q * 4 + 3] = -__expf(a4.w) * LOG2E;
    }
    float Dv = Dp[d];
    const unsigned short* dptr = xzb + (size_t)d * 8192 + r0i;          // delta
    const unsigned short* zptr = xzb + (size_t)(768 + d) * 8192 + r0i;  // z
    const unsigned short* xptr = xcT + (size_t)d * 8192 + r0i;          // xc
    uint4 du[2], xu[2], zu[2];
#pragma unroll
    for (int q = 0; q < 2; q++) {
        du[q] = *(const uint4*)(dptr + q * 8);
        xu[q] = *(const uint4*)(xptr + q * 8);
        zu[q] = *(const uint4*)(zptr + q * 8);
    }
    float h[16];
    {
        const unsigned short* gp = G + (((size_t)(b * NCH + c)) * 768 + d) * 16;
        ld_bf8(gp, h);
        ld_bf8(gp + 8, h + 8);
    }
#pragma unroll
    for (int q = 0; q < 2; q++) {
        float dv[8], xv[8], zv[8];
        ub8(du[q], dv);
        ub8(xu[q], xv);
        ub8(zu[q], zv);
#pragma unroll
        for (int j = 0; j < 8; j++) {
            int t = q * 8 + j;
            float dx = dv[j] * xv[j];
            float Bt[16], Ct[16];
            *(float4*)&Bt[0]  = *(const float4*)(Bu + t * 32);
            *(float4*)&Bt[4]  = *(const float4*)(Bu + t * 32 + 4);
            *(float4*)&Bt[8]  = *(const float4*)(Bu + t * 32 + 8);
            *(float4*)&Bt[12] = *(const float4*)(Bu + t * 32 + 12);
            *(float4*)&Ct[0]  = *(const float4*)(Bu + t * 32 + 16);
            *(float4*)&Ct[4]  = *(const float4*)(Bu + t * 32 + 20);
            *(float4*)&Ct[8]  = *(const float4*)(Bu + t * 32 + 24);
            *(float4*)&Ct[12] = *(const float4*)(Bu + t * 32 + 28);
            float p0 = 0.f, p1 = 0.f, p2 = 0.f, p3 = 0.f;
#pragma unroll
            for (int n = 0; n < 16; n += 4) {
                h[n + 0] = fmaf(fexp2(dv[j] * Avl[n + 0]), h[n + 0], dx * Bt[n + 0]);
                h[n + 1] = fmaf(fexp2(dv[j] * Avl[n + 1]), h[n + 1], dx * Bt[n + 1]);
                h[n + 2] = fmaf(fexp2(dv[j] * Avl[n + 2]), h[n + 2], dx * Bt[n + 2]);
                h[n + 3] = fmaf(fexp2(dv[j] * Avl[n + 3]), h[n + 3], dx * Bt[n + 3]);
                p0 = fmaf(h[n + 0], Ct[n + 0], p0);
                p1 = fmaf(h[n + 1], Ct[n + 1], p1);
                p2 = fmaf(h[n + 2], Ct[n + 2], p2);
                p3 = fmaf(h[n + 3], Ct[n + 3], p3);
            }
            float p = (p0 + p1) + (p2 + p3);
            float zz = zv[j];
            float sig = frcp(1.f + __expf(-zz));
            ly[wv * 16 + t][lane] = f2b1(fmaf(Dv, xv[j], p) * zz * sig);
        }
    }
    __syncthreads();
    size_t rb = (size_t)b * 1024 + (size_t)cg * 64;
#pragma unroll
    for (int k = 0; k < 2; k++) {
        int i = tid + k * 256;
        int row = i >> 3, sg = i & 7;
        uint4 v = *(const uint4*)&ly[row][sg * 8];
        *(uint4*)(yR + (size_t)(rb + row) * 768 + dg * 64 + sg * 8) = v;
    }
}

// ---------------------------------------------------------------- launch
extern "C" void kernel_launch(void* const* d_in, const int* in_sizes, int n_in,
                              void* d_out, int out_size, void* d_ws, size_t ws_size,
                              hipStream_t stream) {
    const float* x    = (const float*)d_in[0];
    const float* ln_g = (const float*)d_in[1];
    const float* ln_b = (const float*)d_in[2];
    const float* mw1  = (const float*)d_in[3];
    const float* mb1  = (const float*)d_in[4];
    const float* mw2  = (const float*)d_in[5];
    const float* mb2  = (const float*)d_in[6];
    const float* inw  = (const float*)d_in[7];
    const float* cw   = (const float*)d_in[8];
    const float* cb   = (const float*)d_in[9];
    const float* xpw  = (const float*)d_in[10];
    const float* dtw  = (const float*)d_in[11];
    const float* dtb  = (const float*)d_in[12];
    const float* alog = (const float*)d_in[13];
    const float* Dp   = (const float*)d_in[14];
    const float* outw = (const float*)d_in[15];
    float* out = (float*)d_out;

    // ws: 68.7 MB total (ws_size = 256 MiB)
    char* ws = (char*)d_ws;
    unsigned short* xzb = (unsigned short*)(ws);            // xz_T [1536][8192] bf16
    float* BCT = (float*)(ws + 25165824);                   // BCT [8192][32] f32
    float* xg  = (float*)(ws + 26214400);                   // 8192*4
    int*  vert = (int*)(ws + 26247168);                     // 8*4 (+pad)
    unsigned short* G = (unsigned short*)(ws + 26248192);   // [8][64][768][16] bf16
    float* sumd = (float*)(ws + 38831104);                  // [8][64][768] f32
    unsigned short* inwT  = (unsigned short*)(ws + 40403968);  // [1536][384] bf16
    unsigned short* dtwTp = (unsigned short*)(ws + 41583616);  // [896][768]  bf16
    unsigned short* outwT = (unsigned short*)(ws + 42959872);  // [384][768]  bf16
    unsigned short* xcR   = (unsigned short*)(ws + 43549696);  // [8192][768] bf16
    unsigned short* yR    = (unsigned short*)(ws + 56132608);  // [8192][768] bf16 (ends 68,715,520)

    unsigned short* xnb = (unsigned short*)d_out;  // d_out: xn(bf16) -> xc_T(bf16) -> out(f32)
    unsigned short* xcT = (unsigned short*)d_out;

    k_ln<<<2048, 256, 0, stream>>>(x, ln_g, ln_b, xnb, xg);
    k_dir<<<8, 256, 0, stream>>>(xg, mw1, mb1, mw2, mb2, vert);
    k_prep<<<1536, 256, 0, stream>>>(inw, dtw, xpw, outw, inwT, dtwTp, outwT);
    // xz_T = (gather(xn) @ in_proj)^T
    k_mfma<0><<<12 * 64, 256, 0, stream>>>(inwT, xnb, xzb, nullptr, nullptr, vert);
    // xc = silu(conv(xz)): writes xc_T (d_out) + xc_rm (ws)
    k_conv<<<12 * 64, 256, 0, stream>>>(xzb, cw, cb, xcT, xcR);
    // delta_T = softplus(xc @ dt_w + dt_b)^T + BCT
    k_mfma<1><<<7 * 64, 256, 0, stream>>>(dtwTp, xcR, xzb, dtb, (const float*)BCT, nullptr);
    k_scan1<<<1536, 256, 0, stream>>>(xzb, xcT, BCT, alog, G, sumd);
    k_scan2<<<8 * 48, 256, 0, stream>>>(G, sumd, alog);
    k_scan3<<<1536, 256, 0, stream>>>(xzb, xcT, BCT, alog, Dp, G, yR);
    // out = x + y @ out_proj
    k_mfma<2><<<3 * 64, 256, 0, stream>>>(yR, outwT, out, nullptr, x, nullptr);
}

// Round 17
// 152.811 us; speedup vs baseline: 2.1117x; 2.1117x over previous
//
#include <hip/hip_runtime.h>
#include <hip/hip_bf16.h>
#include <math.h>

#define NPOS 8192   // B*H*W = 8*32*32
#define DIMC 384
#define DIN 768
#define DST 16
#define CHUNK 16
#define NCH 64      // 1024 / CHUNK

typedef unsigned int uint;
typedef __attribute__((ext_vector_type(8))) short bf16x8;
typedef __attribute__((ext_vector_type(4))) float f32x4;

__device__ __forceinline__ float b2f(unsigned short u) {
    return __uint_as_float(((unsigned int)u) << 16);
}
__device__ __forceinline__ uint cvt_pk(float lo, float hi) {
    uint r;
    asm("v_cvt_pk_bf16_f32 %0, %1, %2" : "=v"(r) : "v"(lo), "v"(hi));
    return r;
}
__device__ __forceinline__ unsigned short f2b1(float f) {
    return (unsigned short)cvt_pk(f, f);
}
__device__ __forceinline__ float frcp(float x) {
    float r;
    asm("v_rcp_f32 %0, %1" : "=v"(r) : "v"(x));
    return r;
}
__device__ __forceinline__ float fexp2(float x) {   // 2^x, 1 instr
    float r;
    asm("v_exp_f32 %0, %1" : "=v"(r) : "v"(x));
    return r;
}
__device__ __forceinline__ void ub8(uint4 u, float* o) {
    o[0] = b2f((unsigned short)(u.x & 0xffff));
    o[1] = b2f((unsigned short)(u.x >> 16));
    o[2] = b2f((unsigned short)(u.y & 0xffff));
    o[3] = b2f((unsigned short)(u.y >> 16));
    o[4] = b2f((unsigned short)(u.z & 0xffff));
    o[5] = b2f((unsigned short)(u.z >> 16));
    o[6] = b2f((unsigned short)(u.w & 0xffff));
    o[7] = b2f((unsigned short)(u.w >> 16));
}
__device__ __forceinline__ void ld_bf8(const unsigned short* p, float* o) {
    ub8(*(const uint4*)p, o);
}
__device__ __forceinline__ uint4 pack_bf8(const float* o) {
    uint4 p;
    p.x = cvt_pk(o[0], o[1]);
    p.y = cvt_pk(o[2], o[3]);
    p.z = cvt_pk(o[4], o[5]);
    p.w = cvt_pk(o[6], o[7]);
    return p;
}
#define LOG2E 1.442695040888963f

// ---------------------------------------------------------------- LayerNorm -> bf16 xn
__global__ __launch_bounds__(256) void k_ln(const float* __restrict__ x,
        const float* __restrict__ g, const float* __restrict__ bta,
        unsigned short* __restrict__ xnb, float* __restrict__ xg) {
    int wid = blockIdx.x * 4 + (threadIdx.x >> 6);
    int lane = threadIdx.x & 63;
    const float* xr = x + (size_t)wid * DIMC;
    float v[6];
    float s = 0.f, ss = 0.f;
#pragma unroll
    for (int i = 0; i < 6; i++) {
        v[i] = xr[lane + i * 64];
        s += v[i]; ss += v[i] * v[i];
    }
#pragma unroll
    for (int m = 32; m; m >>= 1) { s += __shfl_xor(s, m); ss += __shfl_xor(ss, m); }
    float mu = s * (1.f / DIMC);
    float var = ss * (1.f / DIMC) - mu * mu;
    float rstd = rsqrtf(var + 1e-5f);
    unsigned short* xnr = xnb + (size_t)wid * DIMC;
    float sn = 0.f;
#pragma unroll
    for (int i = 0; i < 6; i++) {
        int c = lane + i * 64;
        float o = (v[i] - mu) * rstd * g[c] + bta[c];
        xnr[c] = f2b1(o);
        sn += o;
    }
#pragma unroll
    for (int m = 32; m; m >>= 1) sn += __shfl_xor(sn, m);
    if (lane == 0) xg[wid] = sn * (1.f / DIMC);
}

// ---------------------------------------------------------------- direction
__global__ __launch_bounds__(256) void k_dir(const float* __restrict__ xg,
        const float* __restrict__ w1, const float* __restrict__ b1,
        const float* __restrict__ w2, const float* __restrict__ b2,
        int* __restrict__ vert) {
    __shared__ float sg[32][32];
    __shared__ float red[4][4];
    int b = blockIdx.x;
    int tid = threadIdx.x;
    for (int i = tid; i < 1024; i += 256) sg[i >> 5][i & 31] = xg[b * 1024 + i];
    __syncthreads();
    float ph = 0, pv = 0, pd = 0, pa = 0;
    const float iks = 1.f / 1.0625f;   // kernel_scale = 34/32 (antialias)
    for (int p = tid; p < 1024; p += 256) {
        int y = p >> 5, xq = p & 31;
        int xl = (xq >= 1) ? xq - 1 : 1;
        int xr2 = (xq <= 30) ? xq + 1 : 30;
        float sf = (y + 0.5f) * 1.0625f - 0.5f;
        int jlo = (int)ceilf(sf - 1.0625f); if (jlo < 0) jlo = 0;
        int jhi = (int)floorf(sf + 1.0625f); if (jhi > 33) jhi = 33;
        float acc = 0.f, wsum = 0.f;
        for (int j = jlo; j <= jhi; j++) {
            float wgt = 1.f - fabsf(sf - j) * iks;
            if (wgt <= 0.f) continue;
            int ry = (j >= 1) ? ((j <= 32) ? j - 1 : 30) : 1;
            acc += wgt * fabsf(sg[ry][xr2] - sg[ry][xl]);
            wsum += wgt;
        }
        float ghr = acc / wsum;
        int yu = (y >= 1) ? y - 1 : 1;
        int yd = (y <= 30) ? y + 1 : 30;
        float sfx = (xq + 0.5f) * 1.0625f - 0.5f;
        int ilo = (int)ceilf(sfx - 1.0625f); if (ilo < 0) ilo = 0;
        int ihi = (int)floorf(sfx + 1.0625f); if (ihi > 33) ihi = 33;
        float accv = 0.f, wsv = 0.f;
        for (int i = ilo; i <= ihi; i++) {
            float wgt = 1.f - fabsf(sfx - i) * iks;
            if (wgt <= 0.f) continue;
            int rx = (i >= 1) ? ((i <= 32) ? i - 1 : 30) : 1;
            accv += wgt * fabsf(sg[yd][rx] - sg[yu][rx]);
            wsv += wgt;
        }
        float gvr = accv / wsv;
        float gd = (ghr + gvr) * 0.5f;
        float ga = fabsf(ghr - gvr);
        float cw = ((y == 0 || y == 31) ? 2.f : 3.f) * ((xq == 0 || xq == 31) ? 2.f : 3.f);
        ph += ghr * cw; pv += gvr * cw; pd += gd * cw; pa += ga * cw;
    }
#pragma unroll
    for (int m = 32; m; m >>= 1) {
        ph += __shfl_xor(ph, m); pv += __shfl_xor(pv, m);
        pd += __shfl_xor(pd, m); pa += __shfl_xor(pa, m);
    }
    int wv = tid >> 6;
    if ((tid & 63) == 0) { red[wv][0] = ph; red[wv][1] = pv; red[wv][2] = pd; red[wv][3] = pa; }
    __syncthreads();
    if (tid == 0) {
        float sc[4];
        for (int k = 0; k < 4; k++)
            sc[k] = (red[0][k] + red[1][k] + red[2][k] + red[3][k]) * (1.f / 9216.f);
        float hdn[32];
        for (int j = 0; j < 32; j++) {
            float a = b1[j];
            for (int i = 0; i < 4; i++) a += sc[i] * w1[i * 32 + j];
            hdn[j] = a > 0.f ? a : 0.f;
        }
        float best = -1e30f; int bi = 0;
        for (int k = 0; k < 4; k++) {
            float a = b2[k];
            for (int j = 0; j < 32; j++) a += hdn[j] * w2[j * 4 + k];
            if (a > best) { best = a; bi = k; }
        }
        vert[b] = (bi == 1) ? 1 : 0;
    }
}

// ---------------------------------------------------------------- unified weight prep
__device__ __forceinline__ void wt_body(const float* __restrict__ W,
        unsigned short* __restrict__ WT, int K, int N, int bid, int tid,
        float (*t)[33]) {
    int nb = N >> 5;
    int n0 = (bid % nb) << 5, k0 = (bid / nb) << 5;
    int kr = tid >> 3, n4 = (tid & 7) << 2;
    float4 v = *(const float4*)(W + (size_t)(k0 + kr) * N + n0 + n4);
    t[kr][n4 + 0] = v.x; t[kr][n4 + 1] = v.y; t[kr][n4 + 2] = v.z; t[kr][n4 + 3] = v.w;
    __syncthreads();
    int nr = tid >> 3, k4 = (tid & 7) << 2;
    ushort4 o;
    o.x = f2b1(t[k4 + 0][nr]); o.y = f2b1(t[k4 + 1][nr]);
    o.z = f2b1(t[k4 + 2][nr]); o.w = f2b1(t[k4 + 3][nr]);
    *(ushort4*)(WT + (size_t)(n0 + nr) * K + k0 + k4) = o;
}

__global__ __launch_bounds__(256) void k_prep(const float* __restrict__ inw,
        const float* __restrict__ dtw, const float* __restrict__ xpw,
        const float* __restrict__ outw,
        unsigned short* __restrict__ inwT, unsigned short* __restrict__ dtwTp,
        unsigned short* __restrict__ outwT) {
    __shared__ float t[32][33];
    int bid = blockIdx.x;
    int tid = threadIdx.x;
    if (bid < 576) {
        wt_body(inw, inwT, 384, 1536, bid, tid, t);
    } else if (bid < 1152) {
        wt_body(dtw, dtwTp, 768, 768, bid - 576, tid, t);
    } else if (bid < 1176) {
        wt_body(xpw, dtwTp + 768 * 768, 768, 32, bid - 1152, tid, t);
    } else if (bid < 1464) {
        wt_body(outw, outwT, 768, 384, bid - 1176, tid, t);
    } else {
        int i = (bid - 1464) * 256 + tid;
        if (i < (96 * 768) / 4)
            *(ushort4*)(dtwTp + 800 * 768 + i * 4) = (ushort4){0, 0, 0, 0};
    }
}

// ---------------------------------------------------------------- MFMA GEMM (round-13 proven)
// 128x128 tile, 4 waves, reg-staged dbuf LDS [r][40] (1-deep), XCD swizzle,
// LDS-transpose epilogue.
template <int MODE>
__global__ __launch_bounds__(256) void k_mfma(
        const unsigned short* __restrict__ op1,
        const unsigned short* __restrict__ op2,
        void* __restrict__ outp,
        const float* __restrict__ bias,
        const float* __restrict__ resid,
        const int* __restrict__ vert) {
    constexpr int K = (MODE == 0) ? 384 : 768;
    constexpr int NK = K / 32;
    constexpr int NBN = (MODE == 0) ? 12 : (MODE == 1 ? 7 : 3);
    __shared__ unsigned short lds[2][2][128 * 40];   // 40 KB; reused as [128][132] epilogue
    int tid = threadIdx.x;
    int bid = blockIdx.x;
    int xcd = bid & 7;
    int ii = bid >> 3;
    int n0 = (ii % NBN) << 7;
    int m0 = ((xcd << 3) + ii / NBN) << 7;
    int drow = tid >> 1, dkh = (tid & 1) << 4;

    size_t g1row, g2row;
    if constexpr (MODE == 0) {
        g1row = (size_t)(n0 + drow) * 384;
        int m = m0 + drow;
        int b = m >> 10, l = m & 1023;
        int src = vert[b] ? (((l & 31) << 5) | (l >> 5)) : l;
        g2row = ((size_t)(b << 10) + src) * 384;
    } else if constexpr (MODE == 1) {
        g1row = (size_t)(n0 + drow) * 768;
        g2row = (size_t)(m0 + drow) * 768;
    } else {
        g1row = (size_t)(m0 + drow) * 768;
        g2row = (size_t)(n0 + drow) * 768;
    }

    f32x4 acc[4][4];
    f32x4 zero = {0.f, 0.f, 0.f, 0.f};
#pragma unroll
    for (int i = 0; i < 4; i++)
#pragma unroll
        for (int j = 0; j < 4; j++) acc[i][j] = zero;

    uint4 s1a, s1b, s2a, s2b;
#define LOADS(k0_)                                              \
    { const unsigned short* p1 = op1 + g1row + (k0_) + dkh;     \
      s1a = *(const uint4*)p1; s1b = *(const uint4*)(p1 + 8);   \
      const unsigned short* p2 = op2 + g2row + (k0_) + dkh;     \
      s2a = *(const uint4*)p2; s2b = *(const uint4*)(p2 + 8); }
#define WRITES(buf_)                                            \
    { *(uint4*)&lds[buf_][0][drow * 40 + dkh] = s1a;            \
      *(uint4*)&lds[buf_][0][drow * 40 + dkh + 8] = s1b;        \
      *(uint4*)&lds[buf_][1][drow * 40 + dkh] = s2a;            \
      *(uint4*)&lds[buf_][1][drow * 40 + dkh + 8] = s2b; }

    int wid = tid >> 6, lane = tid & 63;
    int lr = lane & 15, lg = lane >> 4;
    int o1b = (wid >> 1) << 6;   // op1-row 64-block within tile
    int o2b = (wid & 1) << 6;    // op2-row 64-block within tile

    LOADS(0)
    WRITES(0)
    int cur = 0;
    for (int ks = 0; ks < NK; ks++) {
        int kn = (ks + 1) << 5;
        if (ks + 1 < NK) { LOADS(kn) }
        __syncthreads();
        const unsigned short* L1 = &lds[cur][0][0];
        const unsigned short* L2 = &lds[cur][1][0];
        bf16x8 f1[4], f2[4];
#pragma unroll
        for (int f = 0; f < 4; f++) f1[f] = *(const bf16x8*)&L1[(o1b + f * 16 + lr) * 40 + (lg << 3)];
#pragma unroll
        for (int f = 0; f < 4; f++) f2[f] = *(const bf16x8*)&L2[(o2b + f * 16 + lr) * 40 + (lg << 3)];
#pragma unroll
        for (int i = 0; i < 4; i++)
#pragma unroll
            for (int j = 0; j < 4; j++)
                acc[i][j] = __builtin_amdgcn_mfma_f32_16x16x32_bf16(f1[i], f2[j], acc[i][j], 0, 0, 0);
        if (ks + 1 < NK) { WRITES(cur ^ 1) }
        cur ^= 1;
    }

    if constexpr (MODE <= 1) {
        if (MODE == 1 && n0 == 768) {
            if ((wid >> 1) == 0) {   // o1b == 0: rows 0..63 (only 0..31 used)
                float* BCT_ = (float*)resid;
#pragma unroll
                for (int i = 0; i < 2; i++) {
                    int col = i * 16 + lg * 4;
#pragma unroll
                    for (int j = 0; j < 4; j++) {
                        int mb_ = m0 + o2b + j * 16 + lr;
                        float4 v4;
                        v4.x = acc[i][j][0]; v4.y = acc[i][j][1];
                        v4.z = acc[i][j][2]; v4.w = acc[i][j][3];
                        *(float4*)(BCT_ + (size_t)mb_ * 32 + col) = v4;
                    }
                }
            }
        } else {
            // LDS-transpose epilogue: acc -> lt[128][132] -> coalesced rows
            __syncthreads();
            unsigned short* lt = &lds[0][0][0];
#pragma unroll
            for (int i = 0; i < 4; i++) {
                int nr = o1b + i * 16 + lg * 4;
#pragma unroll
                for (int j = 0; j < 4; j++) {
                    int mc = o2b + j * 16 + lr;
#pragma unroll
                    for (int r = 0; r < 4; r++) {
                        float v = acc[i][j][r];
                        if constexpr (MODE == 1) {
                            v += bias[n0 + nr + r];
                            v = fmaxf(v, 0.f) + __logf(1.f + __expf(-fabsf(v)));   // softplus
                        }
                        lt[(nr + r) * 132 + mc] = f2b1(v);
                    }
                }
            }
            __syncthreads();
            unsigned short* CT = (unsigned short*)outp;
#pragma unroll
            for (int ps = 0; ps < 8; ps++) {
                int row = ps * 16 + (tid >> 4);
                uint4 v = *(const uint4*)&lt[row * 132 + (tid & 15) * 8];
                *(uint4*)(CT + (size_t)(n0 + row) * 8192 + m0 + (tid & 15) * 8) = v;
            }
        }
    } else {
        float* C = (float*)outp;
#pragma unroll
        for (int i = 0; i < 4; i++) {
            int mb_ = m0 + o1b + i * 16 + lg * 4;
#pragma unroll
            for (int j = 0; j < 4; j++) {
                int n = n0 + o2b + j * 16 + lr;
#pragma unroll
                for (int r = 0; r < 4; r++) {
                    int m = mb_ + r;
                    C[(size_t)m * 384 + n] = acc[i][j][r] + resid[(size_t)m * 384 + n];
                }
            }
        }
    }
#undef LOADS
#undef WRITES
}

// ---------------------------------------------------------------- depthwise conv3 + silu
__global__ __launch_bounds__(256) void k_conv(const unsigned short* __restrict__ xzb,
        const float* __restrict__ cw, const float* __restrict__ cb,
        unsigned short* __restrict__ xcT, unsigned short* __restrict__ xcR) {
    __shared__ unsigned short ly[128][64];
    int blk = blockIdx.x;            // 12 dg * 64 mg
    int dg = blk % 12, mg = blk / 12;
    int r0 = mg * 128;
    int tid = threadIdx.x;
    int dl = tid >> 2, tq = tid & 3;
    int d = dg * 64 + dl;
    int t0 = r0 + tq * 32;
    const unsigned short* xr = xzb + (size_t)d * 8192;
    float xx[32];
#pragma unroll
    for (int q = 0; q < 4; q++) ub8(*(const uint4*)(xr + t0 + q * 8), xx + q * 8);
    int l0 = t0 & 1023;
    float xprev = (l0 != 0)   ? b2f(xr[t0 - 1])  : 0.f;
    float xnext = (l0 != 992) ? b2f(xr[t0 + 32]) : 0.f;
    float w0 = cw[d * 3], w1 = cw[d * 3 + 1], w2 = cw[d * 3 + 2], bb = cb[d];
    float o[32];
#pragma unroll
    for (int j = 0; j < 32; j++) {
        float v = bb + w1 * xx[j];
        v += w0 * ((j == 0) ? xprev : xx[j - 1]);
        v += w2 * ((j == 31) ? xnext : xx[j + 1]);
        o[j] = v * frcp(1.f + __expf(-v));
    }
    unsigned short* dstT = xcT + (size_t)d * 8192 + t0;
#pragma unroll
    for (int q = 0; q < 4; q++) *(uint4*)(dstT + q * 8) = pack_bf8(o + q * 8);
#pragma unroll
    for (int j = 0; j < 32; j++) ly[tq * 32 + j][dl] = f2b1(o[j]);
    __syncthreads();
#pragma unroll
    for (int k = 0; k < 4; k++) {
        int i = tid + k * 256;
        int row = i >> 3, sg = i & 7;
        uint4 v = *(const uint4*)&ly[row][sg * 8];
        *(uint4*)(xcR + (size_t)(r0 + row) * 768 + dg * 64 + sg * 8) = v;
    }
}

// ---------------------------------------------------------------- chunked scan (CHUNK=16)
__global__ __launch_bounds__(256) void k_scan1(const unsigned short* __restrict__ xzb,
        const unsigned short* __restrict__ xcT, const float* __restrict__ BCT,
        const float* __restrict__ A_log,
        unsigned short* __restrict__ G, float* __restrict__ sumd) {
    int tid = threadIdx.x;
    int lane = tid & 63;
    int blk = blockIdx.x;              // 8b * 16cg * 12dg
    int dg = blk % 12;
    int cg = (blk / 12) % 16;
    int b  = blk / 192;
    int c = cg * 4 + (tid >> 6);
    int d = dg * 64 + lane;
    int r0i = __builtin_amdgcn_readfirstlane(b * 1024 + c * CHUNK);
    const float* Bu = BCT + (size_t)r0i * 32;   // wave-uniform
    float Avl[16];
#pragma unroll
    for (int q = 0; q < 4; q++) {
        float4 a4 = *(const float4*)(A_log + d * 16 + q * 4);
        Avl[q * 4 + 0] = -__expf(a4.x) * LOG2E;
        Avl[q * 4 + 1] = -__expf(a4.y) * LOG2E;
        Avl[q * 4 + 2] = -__expf(a4.z) * LOG2E;
        Avl[q * 4 + 3] = -__expf(a4.w) * LOG2E;
    }
    const unsigned short* dptr = xzb + (size_t)d * 8192 + r0i;
    const unsigned short* xptr = xcT + (size_t)d * 8192 + r0i;
    uint4 du[2], xu[2];
#pragma unroll
    for (int q = 0; q < 2; q++) {
        du[q] = *(const uint4*)(dptr + q * 8);
        xu[q] = *(const uint4*)(xptr + q * 8);
    }
    float h[16] = {};
    float sd = 0.f;
#pragma unroll
    for (int q = 0; q < 2; q++) {
        float dv[8], xv[8];
        ub8(du[q], dv);
        ub8(xu[q], xv);
#pragma unroll
        for (int j = 0; j < 8; j++) {
            int t = q * 8 + j;
            float dx = dv[j] * xv[j];
            sd += dv[j];
            float Bt[16];
            *(float4*)&Bt[0]  = *(const float4*)(Bu + t * 32);
            *(float4*)&Bt[4]  = *(const float4*)(Bu + t * 32 + 4);
            *(float4*)&Bt[8]  = *(const float4*)(Bu + t * 32 + 8);
            *(float4*)&Bt[12] = *(const float4*)(Bu + t * 32 + 12);
#pragma unroll
            for (int n = 0; n < 16; n++)
                h[n] = fmaf(fexp2(dv[j] * Avl[n]), h[n], dx * Bt[n]);
        }
    }
    unsigned short* gp = G + (((size_t)(b * NCH + c)) * 768 + d) * 16;
    *(uint4*)gp       = pack_bf8(h);
    *(uint4*)(gp + 8) = pack_bf8(h + 8);
    sumd[(size_t)(b * NCH + c) * 768 + d] = sd;
}

__global__ __launch_bounds__(256) void k_scan2(unsigned short* __restrict__ G,
        const float* __restrict__ sumd, const float* __restrict__ A_log) {
    int blk = blockIdx.x;              // 8b * 48dg
    int dg = blk % 48, b = blk / 48;
    int tid = threadIdx.x;
    int dl = tid >> 4, n = tid & 15;
    int d = dg * 16 + dl;
    float Av = -__expf(A_log[d * 16 + n]);
    float H = 0.f;
#pragma unroll 8
    for (int c = 0; c < NCH; c++) {
        size_t gi = (((size_t)(b * NCH + c)) * 768 + d) * 16 + n;
        float Gv = b2f(G[gi]);
        float P = __expf(Av * sumd[(size_t)(b * NCH + c) * 768 + d]);
        G[gi] = f2b1(H);               // carry-in for chunk c
        H = fmaf(P, H, Gv);
    }
}

__global__ __launch_bounds__(256) void k_scan3(const unsigned short* __restrict__ xzb,
        const unsigned short* __restrict__ xcT, const float* __restrict__ BCT,
        const float* __restrict__ A_log, const float* __restrict__ Dp,
        const unsigned short* __restrict__ G, unsigned short* __restrict__ yR) {
    __shared__ unsigned short ly[64][64];   // 8 KB  [t-local][d-local]
    int tid = threadIdx.x;
    int lane = tid & 63;
    int wv = tid >> 6;
    int blk = blockIdx.x;              // 8b * 16cg * 12dg
    int dg = blk % 12;
    int cg = (blk / 12) % 16;
    int b  = blk / 192;
    int c = cg * 4 + wv;
    int d = dg * 64 + lane;
    int r0i = __builtin_amdgcn_readfirstlane(b * 1024 + c * CHUNK);
    const float* Bu = BCT + (size_t)r0i * 32;   // wave-uniform
    float Avl[16];
#pragma unroll
    for (int q = 0; q < 4; q++) {
        float4 a4 = *(const float4*)(A_log + d * 16 + q * 4);
        Avl[q * 4 + 0] = -__expf(a4.x) * LOG2E;
        Avl[q * 4 + 1] = -__expf(a4.y) * LOG2E;
        Avl[q * 4 + 2] = -__expf(a4.z) * LOG2E;
        Avl[q * 4 + 3] = -__expf(a4.w) * LOG2E;
    }
    float Dv = Dp[d];
    const unsigned short* dptr = xzb + (size_t)d * 8192 + r0i;          // delta
    const unsigned short* zptr = xzb + (size_t)(768 + d) * 8192 + r0i;  // z
    const unsigned short* xptr = xcT + (size_t)d * 8192 + r0i;          // xc
    uint4 du[2], xu[2], zu[2];
#pragma unroll
    for (int q = 0; q < 2; q++) {
        du[q] = *(const uint4*)(dptr + q * 8);
        xu[q] = *(const uint4*)(xptr + q * 8);
        zu[q] = *(const uint4*)(zptr + q * 8);
    }
    float h[16];
    {
        const unsigned short* gp = G + (((size_t)(b * NCH + c)) * 768 + d) * 16;
        ld_bf8(gp, h);
        ld_bf8(gp + 8, h + 8);
    }
#pragma unroll
    for (int q = 0; q < 2; q++) {
        float dv[8], xv[8], zv[8];
        ub8(du[q], dv);
        ub8(xu[q], xv);
        ub8(zu[q], zv);
#pragma unroll
        for (int j = 0; j < 8; j++) {
            int t = q * 8 + j;
            float dx = dv[j] * xv[j];
            float Bt[16], Ct[16];
            *(float4*)&Bt[0]  = *(const float4*)(Bu + t * 32);
            *(float4*)&Bt[4]  = *(const float4*)(Bu + t * 32 + 4);
            *(float4*)&Bt[8]  = *(const float4*)(Bu + t * 32 + 8);
            *(float4*)&Bt[12] = *(const float4*)(Bu + t * 32 + 12);
            *(float4*)&Ct[0]  = *(const float4*)(Bu + t * 32 + 16);
            *(float4*)&Ct[4]  = *(const float4*)(Bu + t * 32 + 20);
            *(float4*)&Ct[8]  = *(const float4*)(Bu + t * 32 + 24);
            *(float4*)&Ct[12] = *(const float4*)(Bu + t * 32 + 28);
            float p0 = 0.f, p1 = 0.f, p2 = 0.f, p3 = 0.f;
#pragma unroll
            for (int n = 0; n < 16; n += 4) {
                h[n + 0] = fmaf(fexp2(dv[j] * Avl[n + 0]), h[n + 0], dx * Bt[n + 0]);
                h[n + 1] = fmaf(fexp2(dv[j] * Avl[n + 1]), h[n + 1], dx * Bt[n + 1]);
                h[n + 2] = fmaf(fexp2(dv[j] * Avl[n + 2]), h[n + 2], dx * Bt[n + 2]);
                h[n + 3] = fmaf(fexp2(dv[j] * Avl[n + 3]), h[n + 3], dx * Bt[n + 3]);
                p0 = fmaf(h[n + 0], Ct[n + 0], p0);
                p1 = fmaf(h[n + 1], Ct[n + 1], p1);
                p2 = fmaf(h[n + 2], Ct[n + 2], p2);
                p3 = fmaf(h[n + 3], Ct[n + 3], p3);
            }
            float p = (p0 + p1) + (p2 + p3);
            float zz = zv[j];
            float sig = frcp(1.f + __expf(-zz));
            ly[wv * 16 + t][lane] = f2b1(fmaf(Dv, xv[j], p) * zz * sig);
        }
    }
    __syncthreads();
    size_t rb = (size_t)b * 1024 + (size_t)cg * 64;
#pragma unroll
    for (int k = 0; k < 2; k++) {
        int i = tid + k * 256;
        int row = i >> 3, sg = i & 7;
        uint4 v = *(const uint4*)&ly[row][sg * 8];
        *(uint4*)(yR + (size_t)(rb + row) * 768 + dg * 64 + sg * 8) = v;
    }
}

// ---------------------------------------------------------------- launch
extern "C" void kernel_launch(void* const* d_in, const int* in_sizes, int n_in,
                              void* d_out, int out_size, void* d_ws, size_t ws_size,
                              hipStream_t stream) {
    const float* x    = (const float*)d_in[0];
    const float* ln_g = (const float*)d_in[1];
    const float* ln_b = (const float*)d_in[2];
    const float* mw1  = (const float*)d_in[3];
    const float* mb1  = (const float*)d_in[4];
    const float* mw2  = (const float*)d_in[5];
    const float* mb2  = (const float*)d_in[6];
    const float* inw  = (const float*)d_in[7];
    const float* cw   = (const float*)d_in[8];
    const float* cb   = (const float*)d_in[9];
    const float* xpw  = (const float*)d_in[10];
    const float* dtw  = (const float*)d_in[11];
    const float* dtb  = (const float*)d_in[12];
    const float* alog = (const float*)d_in[13];
    const float* Dp   = (const float*)d_in[14];
    const float* outw = (const float*)d_in[15];
    float* out = (float*)d_out;

    // ws: 68.7 MB total (ws_size = 256 MiB)
    char* ws = (char*)d_ws;
    unsigned short* xzb = (unsigned short*)(ws);            // xz_T [1536][8192] bf16
    float* BCT = (float*)(ws + 25165824);                   // BCT [8192][32] f32
    float* xg  = (float*)(ws + 26214400);                   // 8192*4
    int*  vert = (int*)(ws + 26247168);                     // 8*4 (+pad)
    unsigned short* G = (unsigned short*)(ws + 26248192);   // [8][64][768][16] bf16
    float* sumd = (float*)(ws + 38831104);                  // [8][64][768] f32
    unsigned short* inwT  = (unsigned short*)(ws + 40403968);  // [1536][384] bf16
    unsigned short* dtwTp = (unsigned short*)(ws + 41583616);  // [896][768]  bf16
    unsigned short* outwT = (unsigned short*)(ws + 42959872);  // [384][768]  bf16
    unsigned short* xcR   = (unsigned short*)(ws + 43549696);  // [8192][768] bf16
    unsigned short* yR    = (unsigned short*)(ws + 56132608);  // [8192][768] bf16 (ends 68,715,520)

    unsigned short* xnb = (unsigned short*)d_out;  // d_out: xn(bf16) -> xc_T(bf16) -> out(f32)
    unsigned short* xcT = (unsigned short*)d_out;

    k_ln<<<2048, 256, 0, stream>>>(x, ln_g, ln_b, xnb, xg);
    k_dir<<<8, 256, 0, stream>>>(xg, mw1, mb1, mw2, mb2, vert);
    k_prep<<<1536, 256, 0, stream>>>(inw, dtw, xpw, outw, inwT, dtwTp, outwT);
    // xz_T = (gather(xn) @ in_proj)^T
    k_mfma<0><<<12 * 64, 256, 0, stream>>>(inwT, xnb, xzb, nullptr, nullptr, vert);
    // xc = silu(conv(xz)): writes xc_T (d_out) + xc_rm (ws)
    k_conv<<<12 * 64, 256, 0, stream>>>(xzb, cw, cb, xcT, xcR);
    // delta_T = softplus(xc @ dt_w + dt_b)^T + BCT
    k_mfma<1><<<7 * 64, 256, 0, stream>>>(dtwTp, xcR, xzb, dtb, (const float*)BCT, nullptr);
    k_scan1<<<1536, 256, 0, stream>>>(xzb, xcT, BCT, alog, G, sumd);
    k_scan2<<<8 * 48, 256, 0, stream>>>(G, sumd, alog);
    k_scan3<<<1536, 256, 0, stream>>>(xzb, xcT, BCT, alog, Dp, G, yR);
    // out = x + y @ out_proj
    k_mfma<2><<<3 * 64, 256, 0, stream>>>(yR, outwT, out, nullptr, x, nullptr);
}